// Round 1
// baseline (1421.621 us; speedup 1.0000x reference)
//
#include <hip/hip_runtime.h>
#include <stdint.h>

#define NN   4096
#define BATCH 8
#define IC   256
#define HC   512
#define OC   256
#define MTOT (BATCH * NN)   // 32768

typedef float    f32x4 __attribute__((ext_vector_type(4)));
typedef __bf16   bf16x8 __attribute__((ext_vector_type(8)));
typedef uint16_t u16x8 __attribute__((ext_vector_type(8)));

__device__ __forceinline__ uint16_t f2b(float f) {
  union { float f; uint32_t u; } v; v.f = f;
  return (uint16_t)((v.u + 0x7FFFu + ((v.u >> 16) & 1u)) >> 16);
}

// ---------------- K1: deg -> dinv ----------------
__global__ __launch_bounds__(256) void deg_kernel(const float* __restrict__ A,
                                                  float* __restrict__ dinv) {
  const int row = blockIdx.x;                 // 0..32767 (flat b*N+i)
  const float* ap = A + (size_t)row * NN;
  const int t = threadIdx.x;
  float s = 0.f;
#pragma unroll
  for (int i = 0; i < 4; ++i) {
    f32x4 v = *(const f32x4*)(ap + (t + 256 * i) * 4);
    s += v[0] + v[1] + v[2] + v[3];
  }
#pragma unroll
  for (int off = 32; off > 0; off >>= 1) s += __shfl_xor(s, off, 64);
  __shared__ float red[4];
  if ((t & 63) == 0) red[t >> 6] = s;
  __syncthreads();
  if (t == 0) {
    float deg = red[0] + red[1] + red[2] + red[3] + 1.0f;   // +1 self loop
    dinv[row] = 1.0f / sqrtf(deg);
  }
}

// ---------------- K2/K4: C = dinv .* (A @ W), bf16 out ----------------
// A: [MTOT][KTOT] (f32 or bf16), W: [KTOT][NC] f32, C: [MTOT][NC] bf16
template<bool ABF16, int KTOT, int NC>
__global__ __launch_bounds__(256, 2) void xw_kernel(const void* __restrict__ Av,
                                                    const float* __restrict__ W,
                                                    const float* __restrict__ dinv,
                                                    uint16_t* __restrict__ Cout) {
  constexpr int BM = 128, BN = 128, BK = 64, LDT = 72;
  __shared__ uint16_t as_[BM * LDT];
  __shared__ uint16_t wt_[BN * LDT];
  const int t = threadIdx.x;
  const int m0 = blockIdx.x * BM;
  const int n0 = blockIdx.y * BN;
  const int lane = t & 63, wid = t >> 6;
  const int wm = wid >> 1, wn = wid & 1;      // 2x2 waves, 64x64 each
  f32x4 acc[4][4] = {};

  for (int kt = 0; kt < KTOT / BK; ++kt) {
    const int k0 = kt * BK;
    __syncthreads();
    if constexpr (!ABF16) {
      const float* Ap = (const float*)Av;
      const int c4 = t & 15, r0 = t >> 4;     // r0 0..15
#pragma unroll
      for (int i = 0; i < 8; ++i) {
        int r = r0 + 16 * i;
        f32x4 v = *(const f32x4*)(Ap + (size_t)(m0 + r) * KTOT + k0 + c4 * 4);
        uint32_t lo = f2b(v[0]) | ((uint32_t)f2b(v[1]) << 16);
        uint32_t hi = f2b(v[2]) | ((uint32_t)f2b(v[3]) << 16);
        *(uint2*)&as_[r * LDT + c4 * 4] = make_uint2(lo, hi);
      }
    } else {
      const uint16_t* Ap = (const uint16_t*)Av;
      const int c8 = t & 7, r0 = t >> 3;      // r0 0..31
#pragma unroll
      for (int i = 0; i < 4; ++i) {
        int r = r0 + 32 * i;
        u16x8 v = *(const u16x8*)(Ap + (size_t)(m0 + r) * KTOT + k0 + c8 * 8);
        *(u16x8*)&as_[r * LDT + c8 * 8] = v;
      }
    }
    {   // W tile, stored transposed: wt_[n][k]
      const int n4 = t & 31, kq = t >> 5;     // kq 0..7
#pragma unroll
      for (int i = 0; i < 8; ++i) {
        int k = kq + 8 * i;
        f32x4 v = *(const f32x4*)(W + (size_t)(k0 + k) * NC + n0 + n4 * 4);
        uint16_t hv[4] = { f2b(v[0]), f2b(v[1]), f2b(v[2]), f2b(v[3]) };
#pragma unroll
        for (int w = 0; w < 4; ++w) {
          int we = (w + n4) & 3;              // stagger to spread banks
          wt_[(n4 * 4 + we) * LDT + k] = hv[we];
        }
      }
    }
    __syncthreads();
#pragma unroll
    for (int kk = 0; kk < 2; ++kk) {
      bf16x8 bfr[4], afr[4];
#pragma unroll
      for (int fn = 0; fn < 4; ++fn)
        bfr[fn] = *(const bf16x8*)&wt_[(wn * 64 + fn * 16 + (lane & 15)) * LDT + kk * 32 + (lane >> 4) * 8];
#pragma unroll
      for (int fm = 0; fm < 4; ++fm)
        afr[fm] = *(const bf16x8*)&as_[(wm * 64 + fm * 16 + (lane & 15)) * LDT + kk * 32 + (lane >> 4) * 8];
#pragma unroll
      for (int fm = 0; fm < 4; ++fm)
#pragma unroll
        for (int fn = 0; fn < 4; ++fn)
          acc[fm][fn] = __builtin_amdgcn_mfma_f32_16x16x32_bf16(afr[fm], bfr[fn], acc[fm][fn], 0, 0, 0);
    }
  }
#pragma unroll
  for (int fm = 0; fm < 4; ++fm)
#pragma unroll
    for (int r = 0; r < 4; ++r) {
      int row = m0 + wm * 64 + fm * 16 + (lane >> 4) * 4 + r;
      float dv = dinv[row];
#pragma unroll
      for (int fn = 0; fn < 4; ++fn) {
        int col = n0 + wn * 64 + fn * 16 + (lane & 15);
        Cout[(size_t)row * NC + col] = f2b(acc[fm][fn][r] * dv);
      }
    }
}

// ---------------- AGG: out = dinv .* (Ahat @ Vin) + bias (opt relu) ----------------
// Ahat = A + I folded at staging. Vin: [MTOT][BN_] bf16. BN_ = full output width.
template<int BN_, bool RELU>
__global__ __launch_bounds__(512, 2) void agg_kernel(const float* __restrict__ Amat,
                                                     const uint16_t* __restrict__ Vin,
                                                     const float* __restrict__ dinv,
                                                     const float* __restrict__ bias,
                                                     uint16_t* __restrict__ Hout,
                                                     float* __restrict__ Fout) {
  constexpr int BM = 128, BK = 64, LDT = 72;
  constexpr int FN = BN_ / 64;            // frags per wave in N: 8 or 4
  constexpr int WN = BN_ / 4;             // wave N extent: 128 or 64
  constexpr int CHN = BN_ / 8;            // V col chunks: 64 or 32
  constexpr int VT_TASKS = (64 * CHN) / 512;  // 8 or 4
  constexpr int NT = NN / BK;             // 64

  __shared__ uint16_t as_[BM * LDT];
  __shared__ uint16_t vt_[BN_ * LDT];

  const int t = threadIdx.x;
  const int bid = blockIdx.x;
  const int b = bid & 7;                  // XCD swizzle: one batch per XCD
  const int m0 = (bid >> 3) * BM;
  const int lane = t & 63, wid = t >> 6;
  const int wm = wid >> 2, wn = wid & 3;  // 2 x 4 waves

  const float* Abase = Amat + ((size_t)b * NN + m0) * NN;
  const uint16_t* Vbase = Vin + (size_t)b * NN * BN_;

  const int ac4 = t & 15, ar0 = t >> 4;   // A staging decomposition
  f32x4 apre[4];
  u16x8 vpre[VT_TASKS];

  auto load_tile = [&](int kt) {
    const int jj = kt * BK;
#pragma unroll
    for (int i = 0; i < 4; ++i)
      apre[i] = *(const f32x4*)(Abase + (size_t)(ar0 + 32 * i) * NN + jj + ac4 * 4);
#pragma unroll
    for (int i = 0; i < VT_TASKS; ++i) {
      int tt = i * 512 + t;
      int chunk = tt & (CHN - 1);
      int j = tt / CHN;
      vpre[i] = *(const u16x8*)(Vbase + (size_t)(jj + j) * BN_ + chunk * 8);
    }
  };

  load_tile(0);
  f32x4 acc[4][FN] = {};

  for (int kt = 0; kt < NT; ++kt) {
    const int j0 = kt * BK;
    __syncthreads();
    // ---- write A tile to LDS (bf16, +1 on Ahat diagonal) ----
#pragma unroll
    for (int i = 0; i < 4; ++i) {
      int r = ar0 + 32 * i;
      float f0 = apre[i][0], f1 = apre[i][1], f2c = apre[i][2], f3 = apre[i][3];
      int gc = j0 + ac4 * 4;
      int gr = m0 + r;
      if (gr == gc)          f0 += 1.0f;
      else if (gr == gc + 1) f1 += 1.0f;
      else if (gr == gc + 2) f2c += 1.0f;
      else if (gr == gc + 3) f3 += 1.0f;
      uint32_t lo = f2b(f0) | ((uint32_t)f2b(f1) << 16);
      uint32_t hi = f2b(f2c) | ((uint32_t)f2b(f3) << 16);
      *(uint2*)&as_[r * LDT + ac4 * 4] = make_uint2(lo, hi);
    }
    // ---- write V tile transposed: vt_[n][j] ----
#pragma unroll
    for (int i = 0; i < VT_TASKS; ++i) {
      int tt = i * 512 + t;
      int chunk = tt & (CHN - 1);
      int j = tt / CHN;
#pragma unroll
      for (int e = 0; e < 8; ++e) {
        int ee = (e + chunk) & 7;           // stagger to spread banks
        vt_[(chunk * 8 + ee) * LDT + j] = vpre[i][ee];
      }
    }
    __syncthreads();
    if (kt + 1 < NT) load_tile(kt + 1);     // in flight under MFMA below
    // ---- compute ----
#pragma unroll
    for (int kk = 0; kk < 2; ++kk) {
      bf16x8 bfr[FN], afr[4];
#pragma unroll
      for (int fn = 0; fn < FN; ++fn)
        bfr[fn] = *(const bf16x8*)&vt_[(wn * WN + fn * 16 + (lane & 15)) * LDT + kk * 32 + (lane >> 4) * 8];
#pragma unroll
      for (int fm = 0; fm < 4; ++fm)
        afr[fm] = *(const bf16x8*)&as_[(wm * 64 + fm * 16 + (lane & 15)) * LDT + kk * 32 + (lane >> 4) * 8];
#pragma unroll
      for (int fm = 0; fm < 4; ++fm)
#pragma unroll
        for (int fn = 0; fn < FN; ++fn)
          acc[fm][fn] = __builtin_amdgcn_mfma_f32_16x16x32_bf16(afr[fm], bfr[fn], acc[fm][fn], 0, 0, 0);
    }
  }
  // ---- epilogue ----
#pragma unroll
  for (int fm = 0; fm < 4; ++fm)
#pragma unroll
    for (int r = 0; r < 4; ++r) {
      int rowl = wm * 64 + fm * 16 + (lane >> 4) * 4 + r;
      int grow = b * NN + m0 + rowl;
      float dv = dinv[grow];
#pragma unroll
      for (int fn = 0; fn < FN; ++fn) {
        int col = wn * WN + fn * 16 + (lane & 15);
        float v = acc[fm][fn][r] * dv + bias[col];
        if constexpr (RELU) {
          v = fmaxf(v, 0.0f);
          Hout[(size_t)grow * BN_ + col] = f2b(v);
        } else {
          Fout[(size_t)grow * BN_ + col] = v;
        }
      }
    }
}

extern "C" void kernel_launch(void* const* d_in, const int* in_sizes, int n_in,
                              void* d_out, int out_size, void* d_ws, size_t ws_size,
                              hipStream_t stream) {
  const float* x  = (const float*)d_in[0];
  const float* A  = (const float*)d_in[1];
  const float* W1 = (const float*)d_in[2];
  const float* b1 = (const float*)d_in[3];
  const float* W2 = (const float*)d_in[4];
  const float* b2 = (const float*)d_in[5];
  float* out = (float*)d_out;

  char* ws = (char*)d_ws;
  float*    dinv = (float*)ws;                                   // 128 KB
  uint16_t* V1   = (uint16_t*)(ws + 131072);                     // 32 MB
  uint16_t* H    = (uint16_t*)(ws + 131072 + 33554432);          // 32 MB
  uint16_t* V2   = (uint16_t*)(ws + 131072 + 2 * 33554432);      // 16 MB
  // total 84,017,152 bytes of d_ws used

  deg_kernel<<<MTOT, 256, 0, stream>>>(A, dinv);
  xw_kernel<false, IC, HC><<<dim3(MTOT / 128, HC / 128), 256, 0, stream>>>(x, W1, dinv, V1);
  agg_kernel<HC, true><<<256, 512, 0, stream>>>(A, V1, dinv, b1, H, nullptr);
  xw_kernel<true, HC, OC><<<dim3(MTOT / 128, OC / 128), 256, 0, stream>>>(H, W2, dinv, V2);
  agg_kernel<OC, false><<<256, 512, 0, stream>>>(A, V2, dinv, b2, nullptr, out);
}

// Round 2
// 1202.500 us; speedup vs baseline: 1.1822x; 1.1822x over previous
//
#include <hip/hip_runtime.h>
#include <stdint.h>

#define NN   4096
#define BATCH 8
#define IC   256
#define HC   512
#define OC   256

typedef float    f32x4  __attribute__((ext_vector_type(4)));
typedef __bf16   bf16x8 __attribute__((ext_vector_type(8)));
typedef uint16_t u16x8  __attribute__((ext_vector_type(8)));
typedef uint16_t u16x4  __attribute__((ext_vector_type(4)));

__device__ __forceinline__ uint16_t f2b(float f) {
  union { float f; uint32_t u; } v; v.f = f;
  return (uint16_t)((v.u + 0x7FFFu + ((v.u >> 16) & 1u)) >> 16);
}

// async global->LDS, 16B per lane; lds must be wave-uniform base
__device__ __forceinline__ void gl_lds16(const void* g, void* l) {
  __builtin_amdgcn_global_load_lds(
      (const __attribute__((address_space(1))) uint32_t*)g,
      (__attribute__((address_space(3))) uint32_t*)l, 16, 0, 0);
}

// ---------------- K1: rowsum -> dinv ----------------
__global__ __launch_bounds__(256) void deg_kernel(const float* __restrict__ A,
                                                  float* __restrict__ dinv) {
  const int row = blockIdx.x;                  // flat b*N+i
  const float* ap = A + (size_t)row * NN;
  const int t = threadIdx.x;
  float s = 0.f;
#pragma unroll
  for (int i = 0; i < 4; ++i) {
    f32x4 v = *(const f32x4*)(ap + (t + 256 * i) * 4);
    s += v[0] + v[1] + v[2] + v[3];
  }
#pragma unroll
  for (int off = 32; off > 0; off >>= 1) s += __shfl_xor(s, off, 64);
  __shared__ float red[4];
  if ((t & 63) == 0) red[t >> 6] = s;
  __syncthreads();
  if (t == 0) {
    float deg = red[0] + red[1] + red[2] + red[3] + 1.0f;   // self loop
    dinv[row] = 1.0f / sqrtf(deg);
  }
}

// ---------------- prep: Anorm bf16, tiled+swizzled ----------------
// Anorm layout: [b][mt(64)][kt(64)][row 64][slot 8][8 elems]; slot s holds
// k-group g = s ^ (row&7). Tile (b,mt,kt) = 8192 B contiguous.
__global__ __launch_bounds__(256) void prep_kernel(const float* __restrict__ A,
                                                   const float* __restrict__ dinv,
                                                   uint16_t* __restrict__ Anorm) {
  const int bid = blockIdx.x;                  // 2048 blocks
  const int b = bid & 7, mt = (bid >> 3) & 63, kq = bid >> 9;
  const int t = threadIdx.x;
  const float* Ab = A + ((size_t)b * NN + mt * 64) * NN;
  const float* dv = dinv + b * NN;
  uint16_t* out = Anorm + ((size_t)(b * 64 + mt)) * 64 * 4096;
  for (int kt = kq * 16; kt < kq * 16 + 16; ++kt) {
#pragma unroll
    for (int it = 0; it < 2; ++it) {
      int tt = it * 256 + t;
      int r = tt >> 3, g = tt & 7;
      int i = mt * 64 + r;
      int j0 = kt * 64 + g * 8;
      const float* ap = Ab + (size_t)r * NN + j0;
      f32x4 a0 = *(const f32x4*)ap;
      f32x4 a1 = *(const f32x4*)(ap + 4);
      float dvi = dv[i];
      f32x4 d0 = *(const f32x4*)(dv + j0);
      f32x4 d1 = *(const f32x4*)(dv + j0 + 4);
      int dj = i - j0;
      u16x8 o;
#pragma unroll
      for (int e = 0; e < 4; ++e) {
        float v0 = (a0[e] + ((dj == e) ? 1.f : 0.f)) * dvi * d0[e];
        float v1 = (a1[e] + ((dj == e + 4) ? 1.f : 0.f)) * dvi * d1[e];
        o[e] = f2b(v0);
        o[e + 4] = f2b(v1);
      }
      *(u16x8*)(out + ((size_t)kt * 64 + r) * 64 + (g ^ (r & 7)) * 8) = o;
    }
  }
}

// ---------------- xw: Vt = (X @ W)^T, swizzled-tiled bf16 ----------------
// Vt layout: [b][kt(64)][n(NC)][slot 8][8 elems], slot s holds k-group s^(n&7)
template<bool ABF16, int KTOT, int NC>
__global__ __launch_bounds__(256, 2) void xw_kernel(const void* __restrict__ Av,
                                                    const float* __restrict__ W,
                                                    uint16_t* __restrict__ Vt) {
  constexpr int LDT = 72;
  __shared__ uint16_t smem[18432];             // as_[128*72] + wt_[128*72]
  uint16_t* as_ = smem;
  uint16_t* wt_ = smem + 9216;
  const int t = threadIdx.x;
  const int m0 = blockIdx.x * 128;
  const int n0 = blockIdx.y * 128;
  const int lane = t & 63, wid = t >> 6;
  const int wm = wid >> 1, wn = wid & 1;
  f32x4 acc[4][4] = {};

  for (int kt = 0; kt < KTOT / 64; ++kt) {
    const int k0 = kt * 64;
    __syncthreads();
    if constexpr (!ABF16) {
      const float* Ap = (const float*)Av;
      const int c4 = t & 15, r0 = t >> 4;
#pragma unroll
      for (int i = 0; i < 8; ++i) {
        int r = r0 + 16 * i;
        f32x4 v = *(const f32x4*)(Ap + (size_t)(m0 + r) * KTOT + k0 + c4 * 4);
        uint32_t lo = f2b(v[0]) | ((uint32_t)f2b(v[1]) << 16);
        uint32_t hi = f2b(v[2]) | ((uint32_t)f2b(v[3]) << 16);
        *(uint2*)&as_[r * LDT + c4 * 4] = make_uint2(lo, hi);
      }
    } else {
      const uint16_t* Ap = (const uint16_t*)Av;
      const int c8 = t & 7, r0 = t >> 3;
#pragma unroll
      for (int i = 0; i < 4; ++i) {
        int r = r0 + 32 * i;
        u16x8 v = *(const u16x8*)(Ap + (size_t)(m0 + r) * KTOT + k0 + c8 * 8);
        *(u16x8*)&as_[r * LDT + c8 * 8] = v;
      }
    }
    {   // W tile transposed: wt_[n][k]
      const int n4 = t & 31, kq = t >> 5;
#pragma unroll
      for (int i = 0; i < 8; ++i) {
        int k = kq + 8 * i;
        f32x4 v = *(const f32x4*)(W + (size_t)(k0 + k) * NC + n0 + n4 * 4);
        uint16_t hv[4] = { f2b(v[0]), f2b(v[1]), f2b(v[2]), f2b(v[3]) };
#pragma unroll
        for (int w = 0; w < 4; ++w) {
          int we = (w + n4) & 3;
          wt_[(n4 * 4 + we) * LDT + k] = hv[we];
        }
      }
    }
    __syncthreads();
#pragma unroll
    for (int kk = 0; kk < 2; ++kk) {
      bf16x8 bfr[4], afr[4];
#pragma unroll
      for (int fn = 0; fn < 4; ++fn)
        bfr[fn] = *(const bf16x8*)&wt_[(wn * 64 + fn * 16 + (lane & 15)) * LDT + kk * 32 + (lane >> 4) * 8];
#pragma unroll
      for (int fm = 0; fm < 4; ++fm)
        afr[fm] = *(const bf16x8*)&as_[(wm * 64 + fm * 16 + (lane & 15)) * LDT + kk * 32 + (lane >> 4) * 8];
#pragma unroll
      for (int fm = 0; fm < 4; ++fm)
#pragma unroll
        for (int fn = 0; fn < 4; ++fn)
          acc[fm][fn] = __builtin_amdgcn_mfma_f32_16x16x32_bf16(afr[fm], bfr[fn], acc[fm][fn], 0, 0, 0);
    }
  }
  // -------- transpose epilogue via LDS bounce, write swizzled Vt --------
  const int b = m0 >> 12;
  const int kl0 = m0 & 4095;
  __syncthreads();
  uint16_t* lv = smem;                         // [128][144]
#pragma unroll
  for (int fm = 0; fm < 4; ++fm)
#pragma unroll
    for (int fn = 0; fn < 4; ++fn) {
      int nloc = wn * 64 + fn * 16 + (lane & 15);
      int ml0  = wm * 64 + fm * 16 + (lane >> 4) * 4;
      u16x4 pk;
      pk[0] = f2b(acc[fm][fn][0]); pk[1] = f2b(acc[fm][fn][1]);
      pk[2] = f2b(acc[fm][fn][2]); pk[3] = f2b(acc[fm][fn][3]);
      *(u16x4*)&lv[nloc * 144 + ml0] = pk;
    }
  __syncthreads();
#pragma unroll
  for (int i = 0; i < 8; ++i) {
    int nloc = (t >> 4) + 16 * i;
    int ch = t & 15;
    u16x8 v = *(const u16x8*)&lv[nloc * 144 + ch * 8];
    int nglob = n0 + nloc;
    int ktv = (kl0 >> 6) + (ch >> 3);
    int s = (ch & 7) ^ (nglob & 7);
    *(u16x8*)(Vt + (((size_t)b * 64 + ktv) * NC + nglob) * 64 + s * 8) = v;
  }
}

// ---------------- agg: out = Anorm @ V (+bias, opt relu) ----------------
// wave = 64m x 64n; block = BN_/64 waves; grid = 8*64 (b = bid&7 -> XCD pin)
template<int BN_, bool RELU>
__global__ __launch_bounds__(BN_, 4) void agg_kernel(const uint16_t* __restrict__ Anorm,
                                                     const uint16_t* __restrict__ Vt,
                                                     const float* __restrict__ bias,
                                                     uint16_t* __restrict__ Hout,
                                                     float* __restrict__ Fout) {
  constexpr int NWAVES = BN_ / 64;
  __shared__ uint16_t as_[64 * 64];            // 8 KB
  __shared__ uint16_t vt_[BN_ * 64];           // 64/32 KB
  const int t = threadIdx.x;
  const int lane = t & 63, wid = t >> 6;
  const int bid = blockIdx.x;
  const int b = bid & 7, mt = bid >> 3;
  const int fr = lane & 15, c = lane >> 4;

  const uint16_t* Abase = Anorm + ((size_t)(b * 64 + mt)) * 64 * 4096;
  const uint16_t* Vbase = Vt + (size_t)b * 64 * BN_ * 64;

  f32x4 acc[4][4] = {};

  for (int kt = 0; kt < 64; ++kt) {
    __syncthreads();
    const uint16_t* At    = Abase + (size_t)kt * 4096;
    const uint16_t* Vtile = Vbase + (size_t)kt * (BN_ * 64);
    for (int ca = wid; ca < 8; ca += NWAVES)
      gl_lds16(At + ca * 512 + lane * 8, &as_[ca * 512]);
#pragma unroll
    for (int i = 0; i < 8; ++i) {
      int cv = wid * 8 + i;
      gl_lds16(Vtile + cv * 512 + lane * 8, &vt_[cv * 512]);
    }
    __syncthreads();                            // drains vmcnt before use
#pragma unroll
    for (int kk = 0; kk < 2; ++kk) {
      bf16x8 afr[4], bfr[4];
#pragma unroll
      for (int fm = 0; fm < 4; ++fm) {
        int row = fm * 16 + fr;
        afr[fm] = *(const bf16x8*)&as_[row * 64 + (((kk << 2) + c) ^ (row & 7)) * 8];
      }
#pragma unroll
      for (int fn = 0; fn < 4; ++fn) {
        int n = wid * 64 + fn * 16 + fr;
        bfr[fn] = *(const bf16x8*)&vt_[n * 64 + (((kk << 2) + c) ^ (n & 7)) * 8];
      }
#pragma unroll
      for (int fm = 0; fm < 4; ++fm)
#pragma unroll
        for (int fn = 0; fn < 4; ++fn)
          acc[fm][fn] = __builtin_amdgcn_mfma_f32_16x16x32_bf16(afr[fm], bfr[fn], acc[fm][fn], 0, 0, 0);
    }
  }
  // epilogue: + bias (dinv already folded into Anorm)
#pragma unroll
  for (int fm = 0; fm < 4; ++fm)
#pragma unroll
    for (int r = 0; r < 4; ++r) {
      size_t grow = (size_t)b * NN + mt * 64 + fm * 16 + (lane >> 4) * 4 + r;
#pragma unroll
      for (int fn = 0; fn < 4; ++fn) {
        int col = wid * 64 + fn * 16 + fr;
        float v = acc[fm][fn][r] + bias[col];
        if constexpr (RELU) {
          Hout[grow * BN_ + col] = f2b(fmaxf(v, 0.f));
        } else {
          Fout[grow * BN_ + col] = v;
        }
      }
    }
}

extern "C" void kernel_launch(void* const* d_in, const int* in_sizes, int n_in,
                              void* d_out, int out_size, void* d_ws, size_t ws_size,
                              hipStream_t stream) {
  const float* x  = (const float*)d_in[0];
  const float* A  = (const float*)d_in[1];
  const float* W1 = (const float*)d_in[2];
  const float* b1 = (const float*)d_in[3];
  const float* W2 = (const float*)d_in[4];
  const float* b2 = (const float*)d_in[5];
  float* out = (float*)d_out;

  char* ws = (char*)d_ws;
  uint16_t* Anorm = (uint16_t*)ws;                               // 256 MB
  float*    dinv  = (float*)(ws + 268435456);                    // 128 KB
  uint16_t* Vt    = (uint16_t*)(ws + 268435456 + 131072);        // 32 MB (V1, reused for V2)
  uint16_t* H     = (uint16_t*)(ws + 268435456 + 131072 + 33554432); // 32 MB
  // total ws use: 335,675,392 B

  deg_kernel<<<BATCH * NN, 256, 0, stream>>>(A, dinv);
  prep_kernel<<<2048, 256, 0, stream>>>(A, dinv, Anorm);
  xw_kernel<false, IC, HC><<<dim3(256, 4), 256, 0, stream>>>(x, W1, Vt);
  agg_kernel<HC, true><<<512, 512, 0, stream>>>(Anorm, Vt, b1, H, nullptr);
  xw_kernel<true, HC, OC><<<dim3(256, 2), 256, 0, stream>>>(H, W2, Vt);
  agg_kernel<OC, false><<<512, 256, 0, stream>>>(Anorm, Vt, b2, nullptr, out);
}